// Round 13
// baseline (193.719 us; speedup 1.0000x reference)
//
#include <hip/hip_runtime.h>
#include <hip/hip_bf16.h>

#define NTOK 1024     // tokens
#define TKN  2048     // expanded tokens (NTOK * topk)
#define NE   8        // experts
#define NRANK 4
#define IPR  1024     // intermediate per rank
#define HD   2048     // hidden
#define KD   4096     // NRANK * IPR
#define BM   128
#define BN   64
#define BK   64
#define NIT  (KD / BK)   // 64 k-iterations
#define XS   72          // LDS row stride in elements (144 B rows)
#define MAXTILES 24      // worst case sum ceil(c_e/128) = 23
#define NBL  (HD / BN)   // 32 n-blocks
#define NWG  (MAXTILES * NBL)  // 768 blocks, % 8 == 0

typedef __bf16 bf16x8 __attribute__((ext_vector_type(8)));
typedef float f32x4 __attribute__((ext_vector_type(4)));
typedef unsigned short u16x8 __attribute__((ext_vector_type(8)));

static __device__ inline unsigned short f2b(float f) {
  return __builtin_bit_cast(unsigned short, __float2bfloat16(f));
}

// Clobber-free barrier (r11/r12-verified correct): drains LDS ops only; global
// loads stay in flight across it. sched_barrier(0) pins ordering without
// forcing a vmcnt(0) drain.
#define BAR() do {                                            \
    __builtin_amdgcn_sched_barrier(0);                        \
    asm volatile("s_waitcnt lgkmcnt(0)");                     \
    __builtin_amdgcn_sched_barrier(0);                        \
    __builtin_amdgcn_s_barrier();                             \
    __builtin_amdgcn_sched_barrier(0);                        \
  } while (0)

// ---------------- zero d_out (harness doesn't re-zero between replays) ----------------
__global__ __launch_bounds__(256) void zero_kernel(float* __restrict__ p) {
  size_t i = ((size_t)blockIdx.x * 256 + threadIdx.x) * 4;
  *reinterpret_cast<float4*>(p + i) = float4{0.f, 0.f, 0.f, 0.f};
}

// ---------------- routing: top-2 + softmax gates + expert grouping ----------------
__global__ void routing_kernel(const float* __restrict__ logits,
                               float* __restrict__ gate,
                               int* __restrict__ perm,
                               int* __restrict__ tile_e,
                               int* __restrict__ tile_r0,
                               int* __restrict__ tile_nr) {
  __shared__ int cnt[NE];
  __shared__ int cur[NE];
  const int tid = threadIdx.x;   // one thread per token, 1024 threads
  if (tid < NE) cnt[tid] = 0;
  __syncthreads();

  float l[NE];
#pragma unroll
  for (int e = 0; e < NE; ++e) l[e] = logits[tid * NE + e];

  float v0 = l[0]; int i0 = 0;
  float v1 = -3.4e38f; int i1 = 0;
#pragma unroll
  for (int e = 1; e < NE; ++e) {
    if (l[e] > v0) { v1 = v0; i1 = i0; v0 = l[e]; i0 = e; }
    else if (l[e] > v1) { v1 = l[e]; i1 = e; }
  }
  float e1  = expf(v1 - v0);      // v1 <= v0
  float inv = 1.0f / (1.0f + e1);
  gate[2 * tid]     = inv;        // slot 0 = argmax
  gate[2 * tid + 1] = e1 * inv;   // slot 1

  atomicAdd(&cnt[i0], 1);
  atomicAdd(&cnt[i1], 1);
  __syncthreads();

  if (tid == 0) {
    int run = 0, nt = 0;
    for (int e = 0; e < NE; ++e) {
      cur[e] = run;
      int c = cnt[e];
      for (int r0 = 0; r0 < c; r0 += BM) {
        tile_e[nt]  = e;
        tile_r0[nt] = run + r0;
        tile_nr[nt] = (c - r0 < BM) ? (c - r0) : BM;
        ++nt;
      }
      run += c;
    }
    for (; nt < MAXTILES; ++nt) tile_e[nt] = -1;
  }
  __syncthreads();

  int p0 = atomicAdd(&cur[i0], 1); perm[p0] = 2 * tid;
  int p1 = atomicAdd(&cur[i1], 1); perm[p1] = 2 * tid + 1;
}

// ---------------- grouped GEMM: out[tk>>1][h] += gate[tk]*(x[tk].W_e)[h] ----------------
// r12 skeleton + DOUBLE-BUFFERED LDS -> ONE barrier per K-iteration.
// Schedule at iter t:  PACK(tile t+1 -> buf[cur^1])  [regs loaded at iter t-1:
// vmcnt wait window spanned a full COMPUTE+BAR]  ->  LOADREGS(tile t+2)  ->
// COMPUTE(buf[cur])  ->  BAR.  PACK writes the buffer COMPUTE isn't reading;
// the end-of-iter barrier (lgkmcnt-only) covers both visibility and reuse.
__global__ __launch_bounds__(256, 2) void gemm_kernel(
    const float* __restrict__ x,   // f32 [NRANK][TKN][IPR]
    const float* __restrict__ w,   // f32 [NRANK][NE][IPR][HD]
    const int* __restrict__ perm,
    const int* __restrict__ tile_e,
    const int* __restrict__ tile_r0,
    const int* __restrict__ tile_nr,
    const float* __restrict__ gate,
    float* __restrict__ out) {
  // XCD swizzle (r12): tile-major chunks -> same-expert tiles + all n-blocks
  // of a tile co-resident per XCD L2.
  const int id = blockIdx.x;
  const int sw = (id & 7) * (NWG / 8) + (id >> 3);
  const int tile = sw >> 5;          // 0..23  (tile-major)
  const int nb   = sw & 31;          // 0..31  (fastest)

  const int e = tile_e[tile];
  if (e < 0) return;
  const int row0 = tile_r0[tile];
  const int nr   = tile_nr[tile];
  const int n0   = nb * BN;

  __shared__ unsigned short Xs[2][BM][XS];   // bf16 bits, [m][k]  (2 x 18 KB)
  __shared__ unsigned short Ws[2][BN][XS];   // bf16 bits, [n][k]  (2 x  9 KB)

  const int tid  = threadIdx.x;
  const int lane = tid & 63;
  const int wid  = tid >> 6;   // 0..3
  const int wr   = wid >> 1;   // 0..1 : 64-row stripe
  const int wc   = wid & 1;    // 0..1 : 32-col stripe

  // ---- X staging coords: 4 passes; 8 threads per row, 32 B (8 f32) each ----
  const int xr = tid >> 3;          // 0..31 (row within pass)
  const int xc = (tid & 7) << 3;    // k-offset 0,8,...,56
  int xtk[4];
#pragma unroll
  for (int p = 0; p < 4; ++p) {
    const int row = p * 32 + xr;
    xtk[p] = (row < nr) ? perm[row0 + row] : -1;
  }

  // ---- W staging coords: one n-column per thread, 16 k-values ----
  const int wn  = tid & 63;          // n within tile (consecutive lanes -> consecutive n)
  const int wkq = (tid >> 6) << 4;   // 0,16,32,48 (k-quarter per wave)

  // single raw-f32 prefetch bank (loaded at iter t, packed at iter t+1)
  float4 xf[4][2];
  float  wv[16];

#define LOADREGS(KT) do {                                                        \
    const int r_  = (KT) >> 10;                                                  \
    const int i0_ = (KT) & 1023;                                                 \
    _Pragma("unroll")                                                            \
    for (int p_ = 0; p_ < 4; ++p_) {                                             \
      if (xtk[p_] >= 0) {                                                        \
        const float* sp_ = x + ((size_t)r_ * TKN + xtk[p_]) * IPR + i0_ + xc;    \
        xf[p_][0] = *reinterpret_cast<const float4*>(sp_);                       \
        xf[p_][1] = *reinterpret_cast<const float4*>(sp_ + 4);                   \
      } else {                                                                   \
        xf[p_][0] = float4{0.f, 0.f, 0.f, 0.f};                                  \
        xf[p_][1] = float4{0.f, 0.f, 0.f, 0.f};                                  \
      }                                                                          \
    }                                                                            \
    const float* wp_ = w + (((size_t)r_ * NE + e) * IPR + i0_ + wkq) * HD + n0 + wn; \
    _Pragma("unroll")                                                            \
    for (int j_ = 0; j_ < 16; ++j_) wv[j_] = wp_[(size_t)j_ * HD];               \
  } while (0)

#define PACKWRITE(B) do {                                                        \
    _Pragma("unroll")                                                            \
    for (int p_ = 0; p_ < 4; ++p_) {                                             \
      u16x8 v_;                                                                  \
      v_[0] = f2b(xf[p_][0].x); v_[1] = f2b(xf[p_][0].y);                        \
      v_[2] = f2b(xf[p_][0].z); v_[3] = f2b(xf[p_][0].w);                        \
      v_[4] = f2b(xf[p_][1].x); v_[5] = f2b(xf[p_][1].y);                        \
      v_[6] = f2b(xf[p_][1].z); v_[7] = f2b(xf[p_][1].w);                        \
      *reinterpret_cast<u16x8*>(&Xs[B][p_ * 32 + xr][xc]) = v_;                  \
    }                                                                            \
    u16x8 a_, b_;                                                                \
    a_[0] = f2b(wv[0]);  a_[1] = f2b(wv[1]);  a_[2] = f2b(wv[2]);                \
    a_[3] = f2b(wv[3]);  a_[4] = f2b(wv[4]);  a_[5] = f2b(wv[5]);                \
    a_[6] = f2b(wv[6]);  a_[7] = f2b(wv[7]);                                     \
    b_[0] = f2b(wv[8]);  b_[1] = f2b(wv[9]);  b_[2] = f2b(wv[10]);               \
    b_[3] = f2b(wv[11]); b_[4] = f2b(wv[12]); b_[5] = f2b(wv[13]);               \
    b_[6] = f2b(wv[14]); b_[7] = f2b(wv[15]);                                    \
    *reinterpret_cast<u16x8*>(&Ws[B][wn][wkq])     = a_;                         \
    *reinterpret_cast<u16x8*>(&Ws[B][wn][wkq + 8]) = b_;                         \
  } while (0)

  f32x4 acc[4][2];
#pragma unroll
  for (int a = 0; a < 4; ++a)
#pragma unroll
    for (int b = 0; b < 2; ++b) acc[a][b] = f32x4{0.f, 0.f, 0.f, 0.f};

  const int lrow = lane & 15;
  const int lk   = (lane >> 4) << 3;   // 0,8,16,24

#define COMPUTE(B) do {                                                          \
    _Pragma("unroll")                                                            \
    for (int ks_ = 0; ks_ < 2; ++ks_) {                                          \
      bf16x8 af_[4], bf_[2];                                                     \
      _Pragma("unroll")                                                          \
      for (int mi_ = 0; mi_ < 4; ++mi_)                                          \
        af_[mi_] = __builtin_bit_cast(bf16x8, *reinterpret_cast<const u16x8*>(   \
            &Xs[B][wr * 64 + mi_ * 16 + lrow][ks_ * 32 + lk]));                  \
      _Pragma("unroll")                                                          \
      for (int ni_ = 0; ni_ < 2; ++ni_)                                          \
        bf_[ni_] = __builtin_bit_cast(bf16x8, *reinterpret_cast<const u16x8*>(   \
            &Ws[B][wc * 32 + ni_ * 16 + lrow][ks_ * 32 + lk]));                  \
      _Pragma("unroll")                                                          \
      for (int mi_ = 0; mi_ < 4; ++mi_)                                          \
        _Pragma("unroll")                                                        \
        for (int ni_ = 0; ni_ < 2; ++ni_)                                        \
          acc[mi_][ni_] = __builtin_amdgcn_mfma_f32_16x16x32_bf16(               \
              af_[mi_], bf_[ni_], acc[mi_][ni_], 0, 0, 0);                       \
    }                                                                            \
  } while (0)

  // prologue: tile0 -> buf0; tile1 loaded into regs
  LOADREGS(0);
  PACKWRITE(0);
  LOADREGS(BK);
  BAR();

  int cur = 0;
  for (int t = 0; t < NIT; ++t) {
    if (t + 1 < NIT) PACKWRITE(cur ^ 1);     // pack tile t+1 (regs from iter t-1)
    if (t + 2 < NIT) LOADREGS((t + 2) * BK); // issue tile t+2 loads
    COMPUTE(cur);                            // consume tile t
    BAR();                                   // one lgkm-only barrier per iter
    cur ^= 1;
  }

  // ---- epilogue: gate * acc, atomicAdd into f32 out (exactly 2 adds/element) ----
  const int mb = (lane >> 4) << 2;
#pragma unroll
  for (int mi = 0; mi < 4; ++mi) {
#pragma unroll
    for (int q = 0; q < 4; ++q) {
      const int m = wr * 64 + mi * 16 + mb + q;
      if (m < nr) {
        const int tk = perm[row0 + m];
        const float g = gate[tk];
        float* dst = out + (size_t)(tk >> 1) * HD + n0 + wc * 32 + lrow;
#pragma unroll
        for (int ni = 0; ni < 2; ++ni)
          atomicAdd(&dst[ni * 16], g * acc[mi][ni][q]);
      }
    }
  }
#undef LOADREGS
#undef PACKWRITE
#undef COMPUTE
}

extern "C" void kernel_launch(void* const* d_in, const int* in_sizes, int n_in,
                              void* d_out, int out_size, void* d_ws, size_t ws_size,
                              hipStream_t stream) {
  const float* x      = (const float*)d_in[0];  // f32 (upcast from fp16)
  const float* w      = (const float*)d_in[1];  // f32 (upcast from fp16)
  const float* logits = (const float*)d_in[2];
  // d_in[3] = topk (constant 2), unused

  char* ws = (char*)d_ws;
  float* gate    = (float*)(ws + 0);          // TKN floats   (8 KB)
  int*   perm    = (int*)(ws + 8192);         // TKN ints     (8 KB)
  int*   tile_e  = (int*)(ws + 16384);        // MAXTILES ints
  int*   tile_r0 = (int*)(ws + 16384 + 256);
  int*   tile_nr = (int*)(ws + 16384 + 512);

  float* outf = (float*)d_out;                // f32 output [NTOK][HD]

  zero_kernel<<<(NTOK * HD / 4) / 256, 256, 0, stream>>>(outf);
  routing_kernel<<<1, 1024, 0, stream>>>(logits, gate, perm, tile_e, tile_r0, tile_nr);
  gemm_kernel<<<NWG, 256, 0, stream>>>(x, w, perm, tile_e, tile_r0, tile_nr, gate, outf);
}

// Round 14
// 187.359 us; speedup vs baseline: 1.0339x; 1.0339x over previous
//
#include <hip/hip_runtime.h>
#include <hip/hip_bf16.h>

#define NTOK 1024     // tokens
#define TKN  2048     // expanded tokens (NTOK * topk)
#define NE   8        // experts
#define NRANK 4
#define IPR  1024     // intermediate per rank
#define HD   2048     // hidden
#define KD   4096     // NRANK * IPR
#define BM   128
#define BN   64
#define BK   64
#define KSPLIT 2
#define KPS  (KD / KSPLIT)     // 2048 K per split
#define NIT  (KPS / BK)        // 32 k-iterations per block
#define XS   72                // LDS row stride in elements (144 B rows)
#define MAXTILES 24            // worst case sum ceil(c_e/128) = 23
#define NBL  (HD / BN)         // 32 n-blocks
#define NWG  (MAXTILES * KSPLIT * NBL)  // 1536 blocks, % 8 == 0

typedef __bf16 bf16x8 __attribute__((ext_vector_type(8)));
typedef float f32x4 __attribute__((ext_vector_type(4)));
typedef unsigned short u16x8 __attribute__((ext_vector_type(8)));

static __device__ inline unsigned short f2b(float f) {
  return __builtin_bit_cast(unsigned short, __float2bfloat16(f));
}

// Clobber-free barrier (r11/r12-verified): drains LDS ops only; global loads
// stay in flight across it. sched_barrier(0) pins ordering without forcing a
// vmcnt(0) drain.
#define BAR() do {                                            \
    __builtin_amdgcn_sched_barrier(0);                        \
    asm volatile("s_waitcnt lgkmcnt(0)");                     \
    __builtin_amdgcn_sched_barrier(0);                        \
    __builtin_amdgcn_s_barrier();                             \
    __builtin_amdgcn_sched_barrier(0);                        \
  } while (0)

// ---------------- zero d_out (harness doesn't re-zero between replays) ----------------
__global__ __launch_bounds__(256) void zero_kernel(float* __restrict__ p) {
  size_t i = ((size_t)blockIdx.x * 256 + threadIdx.x) * 4;
  *reinterpret_cast<float4*>(p + i) = float4{0.f, 0.f, 0.f, 0.f};
}

// ---------------- routing: top-2 + softmax gates + expert grouping ----------------
__global__ void routing_kernel(const float* __restrict__ logits,
                               float* __restrict__ gate,
                               int* __restrict__ perm,
                               int* __restrict__ tile_e,
                               int* __restrict__ tile_r0,
                               int* __restrict__ tile_nr) {
  __shared__ int cnt[NE];
  __shared__ int cur[NE];
  const int tid = threadIdx.x;   // one thread per token, 1024 threads
  if (tid < NE) cnt[tid] = 0;
  __syncthreads();

  float l[NE];
#pragma unroll
  for (int e = 0; e < NE; ++e) l[e] = logits[tid * NE + e];

  float v0 = l[0]; int i0 = 0;
  float v1 = -3.4e38f; int i1 = 0;
#pragma unroll
  for (int e = 1; e < NE; ++e) {
    if (l[e] > v0) { v1 = v0; i1 = i0; v0 = l[e]; i0 = e; }
    else if (l[e] > v1) { v1 = l[e]; i1 = e; }
  }
  float e1  = expf(v1 - v0);      // v1 <= v0
  float inv = 1.0f / (1.0f + e1);
  gate[2 * tid]     = inv;        // slot 0 = argmax
  gate[2 * tid + 1] = e1 * inv;   // slot 1

  atomicAdd(&cnt[i0], 1);
  atomicAdd(&cnt[i1], 1);
  __syncthreads();

  if (tid == 0) {
    int run = 0, nt = 0;
    for (int e = 0; e < NE; ++e) {
      cur[e] = run;
      int c = cnt[e];
      for (int r0 = 0; r0 < c; r0 += BM) {
        tile_e[nt]  = e;
        tile_r0[nt] = run + r0;
        tile_nr[nt] = (c - r0 < BM) ? (c - r0) : BM;
        ++nt;
      }
      run += c;
    }
    for (; nt < MAXTILES; ++nt) tile_e[nt] = -1;
  }
  __syncthreads();

  int p0 = atomicAdd(&cur[i0], 1); perm[p0] = 2 * tid;
  int p1 = atomicAdd(&cur[i1], 1); perm[p1] = 2 * tid + 1;
}

// ---------------- grouped GEMM (r12 structure + KSPLIT=2) ----------------
// 256 thr = 4 waves (2M x 2N), BM=128, BN=64, K split in halves -> 1536 blocks
// (2x independent iteration streams per CU to overlap the fixed per-iteration
// latency). Depth-1 register prefetch; clobber-free barriers; atomic f32
// epilogue (exactly 4 adds/element -> deterministic).
__global__ __launch_bounds__(256, 3) void gemm_kernel(
    const float* __restrict__ x,   // f32 [NRANK][TKN][IPR]
    const float* __restrict__ w,   // f32 [NRANK][NE][IPR][HD]
    const int* __restrict__ perm,
    const int* __restrict__ tile_e,
    const int* __restrict__ tile_r0,
    const int* __restrict__ tile_nr,
    const float* __restrict__ gate,
    float* __restrict__ out) {
  // XCD swizzle (r12 scheme, ksp folded in): sw = (tile*KSPLIT+ksp)*32 + nb,
  // contiguous chunks of 192 per XCD -> ~3 (tile,ksp) groups x all 32 n-blocks
  // co-resident: same-expert W slices + each tile's X rows live in one L2.
  const int id = blockIdx.x;
  const int sw = (id & 7) * (NWG / 8) + (id >> 3);
  const int nb   = sw & 31;            // fastest
  const int tksp = sw >> 5;            // 0..47
  const int tile = tksp >> 1;
  const int ksp  = tksp & 1;

  const int e = tile_e[tile];
  if (e < 0) return;
  const int row0 = tile_r0[tile];
  const int nr   = tile_nr[tile];
  const int n0   = nb * BN;
  const int kbase = ksp * KPS;

  __shared__ unsigned short Xs[BM][XS];   // bf16 bits, [m][k]  (18 KB)
  __shared__ unsigned short Ws[BN][XS];   // bf16 bits, transposed: [n][k] (9 KB)

  const int tid  = threadIdx.x;
  const int lane = tid & 63;
  const int wid  = tid >> 6;   // 0..3
  const int wr   = wid >> 1;   // 0..1 : 64-row stripe
  const int wc   = wid & 1;    // 0..1 : 32-col stripe

  // ---- X staging coords: 4 passes; 8 threads per row, 32 B (8 f32) each ----
  const int xr = tid >> 3;          // 0..31 (row within pass)
  const int xc = (tid & 7) << 3;    // k-offset 0,8,...,56
  int xtk[4];
#pragma unroll
  for (int p = 0; p < 4; ++p) {
    const int row = p * 32 + xr;
    xtk[p] = (row < nr) ? perm[row0 + row] : -1;
  }

  // ---- W staging coords: one n-column per thread, 16 k-values ----
  const int wn  = tid & 63;          // n within tile (consecutive lanes -> consecutive n)
  const int wkq = (tid >> 6) << 4;   // 0,16,32,48 (k-quarter per wave)

  // single raw-f32 prefetch bank
  float4 xf[4][2];
  float  wv[16];

#define LOADREGS(KT) do {                                                        \
    const int r_  = (KT) >> 10;                                                  \
    const int i0_ = (KT) & 1023;                                                 \
    _Pragma("unroll")                                                            \
    for (int p_ = 0; p_ < 4; ++p_) {                                             \
      if (xtk[p_] >= 0) {                                                        \
        const float* sp_ = x + ((size_t)r_ * TKN + xtk[p_]) * IPR + i0_ + xc;    \
        xf[p_][0] = *reinterpret_cast<const float4*>(sp_);                       \
        xf[p_][1] = *reinterpret_cast<const float4*>(sp_ + 4);                   \
      } else {                                                                   \
        xf[p_][0] = float4{0.f, 0.f, 0.f, 0.f};                                  \
        xf[p_][1] = float4{0.f, 0.f, 0.f, 0.f};                                  \
      }                                                                          \
    }                                                                            \
    const float* wp_ = w + (((size_t)r_ * NE + e) * IPR + i0_ + wkq) * HD + n0 + wn; \
    _Pragma("unroll")                                                            \
    for (int j_ = 0; j_ < 16; ++j_) wv[j_] = wp_[(size_t)j_ * HD];               \
  } while (0)

  f32x4 acc[4][2];
#pragma unroll
  for (int a = 0; a < 4; ++a)
#pragma unroll
    for (int b = 0; b < 2; ++b) acc[a][b] = f32x4{0.f, 0.f, 0.f, 0.f};

  const int lrow = lane & 15;
  const int lk   = (lane >> 4) << 3;   // 0,8,16,24

  LOADREGS(kbase);

  for (int t = 0; t < NIT; ++t) {
    BAR();   // previous compute's LDS reads drained; LDS free

    // ---- write prefetched regs -> LDS (f32 -> bf16) ----
#pragma unroll
    for (int p = 0; p < 4; ++p) {
      u16x8 v;
      v[0] = f2b(xf[p][0].x); v[1] = f2b(xf[p][0].y);
      v[2] = f2b(xf[p][0].z); v[3] = f2b(xf[p][0].w);
      v[4] = f2b(xf[p][1].x); v[5] = f2b(xf[p][1].y);
      v[6] = f2b(xf[p][1].z); v[7] = f2b(xf[p][1].w);
      *reinterpret_cast<u16x8*>(&Xs[p * 32 + xr][xc]) = v;
    }
    {
      u16x8 a, b;
      a[0] = f2b(wv[0]);  a[1] = f2b(wv[1]);  a[2] = f2b(wv[2]);  a[3] = f2b(wv[3]);
      a[4] = f2b(wv[4]);  a[5] = f2b(wv[5]);  a[6] = f2b(wv[6]);  a[7] = f2b(wv[7]);
      b[0] = f2b(wv[8]);  b[1] = f2b(wv[9]);  b[2] = f2b(wv[10]); b[3] = f2b(wv[11]);
      b[4] = f2b(wv[12]); b[5] = f2b(wv[13]); b[6] = f2b(wv[14]); b[7] = f2b(wv[15]);
      *reinterpret_cast<u16x8*>(&Ws[wn][wkq])     = a;
      *reinterpret_cast<u16x8*>(&Ws[wn][wkq + 8]) = b;
    }
    BAR();   // ds_writes visible to all waves

    // ---- prefetch next iteration (overlaps compute below) ----
    if (t + 1 < NIT) LOADREGS(kbase + (t + 1) * BK);

    // ---- compute: 2 k-steps of 32, 4x2 fragments per wave ----
#pragma unroll
    for (int ks = 0; ks < 2; ++ks) {
      bf16x8 af[4], bfr[2];
#pragma unroll
      for (int mi = 0; mi < 4; ++mi)
        af[mi] = __builtin_bit_cast(bf16x8,
            *reinterpret_cast<const u16x8*>(&Xs[wr * 64 + mi * 16 + lrow][ks * 32 + lk]));
#pragma unroll
      for (int ni = 0; ni < 2; ++ni)
        bfr[ni] = __builtin_bit_cast(bf16x8,
            *reinterpret_cast<const u16x8*>(&Ws[wc * 32 + ni * 16 + lrow][ks * 32 + lk]));
#pragma unroll
      for (int mi = 0; mi < 4; ++mi)
#pragma unroll
        for (int ni = 0; ni < 2; ++ni)
          acc[mi][ni] = __builtin_amdgcn_mfma_f32_16x16x32_bf16(af[mi], bfr[ni], acc[mi][ni], 0, 0, 0);
    }
  }

  // ---- epilogue: gate * acc, atomicAdd into f32 out (exactly 4 adds/element) ----
  const int mb = (lane >> 4) << 2;
#pragma unroll
  for (int mi = 0; mi < 4; ++mi) {
#pragma unroll
    for (int q = 0; q < 4; ++q) {
      const int m = wr * 64 + mi * 16 + mb + q;
      if (m < nr) {
        const int tk = perm[row0 + m];
        const float g = gate[tk];
        float* dst = out + (size_t)(tk >> 1) * HD + n0 + wc * 32 + lrow;
#pragma unroll
        for (int ni = 0; ni < 2; ++ni)
          atomicAdd(&dst[ni * 16], g * acc[mi][ni][q]);
      }
    }
  }
#undef LOADREGS
}

extern "C" void kernel_launch(void* const* d_in, const int* in_sizes, int n_in,
                              void* d_out, int out_size, void* d_ws, size_t ws_size,
                              hipStream_t stream) {
  const float* x      = (const float*)d_in[0];  // f32 (upcast from fp16)
  const float* w      = (const float*)d_in[1];  // f32 (upcast from fp16)
  const float* logits = (const float*)d_in[2];
  // d_in[3] = topk (constant 2), unused

  char* ws = (char*)d_ws;
  float* gate    = (float*)(ws + 0);          // TKN floats   (8 KB)
  int*   perm    = (int*)(ws + 8192);         // TKN ints     (8 KB)
  int*   tile_e  = (int*)(ws + 16384);        // MAXTILES ints
  int*   tile_r0 = (int*)(ws + 16384 + 256);
  int*   tile_nr = (int*)(ws + 16384 + 512);

  float* outf = (float*)d_out;                // f32 output [NTOK][HD]

  zero_kernel<<<(NTOK * HD / 4) / 256, 256, 0, stream>>>(outf);
  routing_kernel<<<1, 1024, 0, stream>>>(logits, gate, perm, tile_e, tile_r0, tile_nr);
  gemm_kernel<<<NWG, 256, 0, stream>>>(x, w, perm, tile_e, tile_r0, tile_nr, gate, outf);
}

// Round 15
// 169.779 us; speedup vs baseline: 1.1410x; 1.1035x over previous
//
#include <hip/hip_runtime.h>
#include <hip/hip_bf16.h>

#define NTOK 1024     // tokens
#define TKN  2048     // expanded tokens (NTOK * topk)
#define NE   8        // experts
#define NRANK 4
#define IPR  1024     // intermediate per rank
#define HD   2048     // hidden
#define KD   4096     // NRANK * IPR
#define BM   128
#define BN   64
#define BK   64
#define NIT  (KD / BK)   // 64 k-iterations
#define XS   72          // LDS row stride in elements (144 B rows)
#define MAXTILES 24      // worst case sum ceil(c_e/128) = 23
#define NBL  (HD / BN)   // 32 n-blocks
#define NWG  (MAXTILES * NBL)  // 768 blocks, % 8 == 0

typedef __bf16 bf16x8 __attribute__((ext_vector_type(8)));
typedef float f32x4 __attribute__((ext_vector_type(4)));
typedef unsigned short u16x8 __attribute__((ext_vector_type(8)));

static __device__ inline unsigned short f2b(float f) {
  return __builtin_bit_cast(unsigned short, __float2bfloat16(f));
}

// Clobber-free barrier: drains LDS ops only; global loads stay in flight.
// sched_barrier(0) pins ordering without forcing a vmcnt(0) drain.
#define BAR() do {                                            \
    __builtin_amdgcn_sched_barrier(0);                        \
    asm volatile("s_waitcnt lgkmcnt(0)");                     \
    __builtin_amdgcn_sched_barrier(0);                        \
    __builtin_amdgcn_s_barrier();                             \
    __builtin_amdgcn_sched_barrier(0);                        \
  } while (0)

// ---------------- zero d_out (harness doesn't re-zero between replays) ----------------
__global__ __launch_bounds__(256) void zero_kernel(float* __restrict__ p) {
  size_t i = ((size_t)blockIdx.x * 256 + threadIdx.x) * 4;
  *reinterpret_cast<float4*>(p + i) = float4{0.f, 0.f, 0.f, 0.f};
}

// ---------------- routing: top-2 + softmax gates + expert grouping ----------------
__global__ void routing_kernel(const float* __restrict__ logits,
                               float* __restrict__ gate,
                               int* __restrict__ perm,
                               int* __restrict__ tile_e,
                               int* __restrict__ tile_r0,
                               int* __restrict__ tile_nr) {
  __shared__ int cnt[NE];
  __shared__ int cur[NE];
  const int tid = threadIdx.x;   // one thread per token, 1024 threads
  if (tid < NE) cnt[tid] = 0;
  __syncthreads();

  float l[NE];
#pragma unroll
  for (int e = 0; e < NE; ++e) l[e] = logits[tid * NE + e];

  float v0 = l[0]; int i0 = 0;
  float v1 = -3.4e38f; int i1 = 0;
#pragma unroll
  for (int e = 1; e < NE; ++e) {
    if (l[e] > v0) { v1 = v0; i1 = i0; v0 = l[e]; i0 = e; }
    else if (l[e] > v1) { v1 = l[e]; i1 = e; }
  }
  float e1  = expf(v1 - v0);      // v1 <= v0
  float inv = 1.0f / (1.0f + e1);
  gate[2 * tid]     = inv;        // slot 0 = argmax
  gate[2 * tid + 1] = e1 * inv;   // slot 1

  atomicAdd(&cnt[i0], 1);
  atomicAdd(&cnt[i1], 1);
  __syncthreads();

  if (tid == 0) {
    int run = 0, nt = 0;
    for (int e = 0; e < NE; ++e) {
      cur[e] = run;
      int c = cnt[e];
      for (int r0 = 0; r0 < c; r0 += BM) {
        tile_e[nt]  = e;
        tile_r0[nt] = run + r0;
        tile_nr[nt] = (c - r0 < BM) ? (c - r0) : BM;
        ++nt;
      }
      run += c;
    }
    for (; nt < MAXTILES; ++nt) tile_e[nt] = -1;
  }
  __syncthreads();

  int p0 = atomicAdd(&cur[i0], 1); perm[p0] = 2 * tid;
  int p1 = atomicAdd(&cur[i1], 1); perm[p1] = 2 * tid + 1;
}

// ---------------- grouped GEMM (best measured config, r12): ----------------
// out[tk>>1][h] += gate[tk]*(x[tk].W_e)[h]
// 256 thr = 4 waves (2M x 2N), BM=128, BN=64, full K per block (no split).
// Depth-1 register prefetch; clobber-free barriers; atomic f32 epilogue
// (exactly 2 adds/element -> deterministic).
__global__ __launch_bounds__(256, 3) void gemm_kernel(
    const float* __restrict__ x,   // f32 [NRANK][TKN][IPR]
    const float* __restrict__ w,   // f32 [NRANK][NE][IPR][HD]
    const int* __restrict__ perm,
    const int* __restrict__ tile_e,
    const int* __restrict__ tile_r0,
    const int* __restrict__ tile_nr,
    const float* __restrict__ gate,
    float* __restrict__ out) {
  // XCD swizzle for W-slice sharing: HW runs blockIdx id on XCD id%8. Remap so
  // XCD c gets the contiguous sw-chunk [c*96, (c+1)*96) with sw = tile*32+nb:
  // 3 consecutive tiles (usually the same expert -> identical W slices) x all
  // 32 n-blocks (sharing each tile's X rows) co-resident per XCD L2.
  const int id = blockIdx.x;
  const int sw = (id & 7) * (NWG / 8) + (id >> 3);
  const int tile = sw >> 5;          // 0..23  (tile-major)
  const int nb   = sw & 31;          // 0..31  (fastest)

  const int e = tile_e[tile];
  if (e < 0) return;
  const int row0 = tile_r0[tile];
  const int nr   = tile_nr[tile];
  const int n0   = nb * BN;

  __shared__ unsigned short Xs[BM][XS];   // bf16 bits, [m][k]  (18 KB)
  __shared__ unsigned short Ws[BN][XS];   // bf16 bits, transposed: [n][k] (9 KB)

  const int tid  = threadIdx.x;
  const int lane = tid & 63;
  const int wid  = tid >> 6;   // 0..3
  const int wr   = wid >> 1;   // 0..1 : 64-row stripe
  const int wc   = wid & 1;    // 0..1 : 32-col stripe

  // ---- X staging coords: 4 passes; 8 threads per row, 32 B (8 f32) each ----
  const int xr = tid >> 3;          // 0..31 (row within pass)
  const int xc = (tid & 7) << 3;    // k-offset 0,8,...,56
  int xtk[4];
#pragma unroll
  for (int p = 0; p < 4; ++p) {
    const int row = p * 32 + xr;
    xtk[p] = (row < nr) ? perm[row0 + row] : -1;
  }

  // ---- W staging coords: one n-column per thread, 16 k-values ----
  const int wn  = tid & 63;          // n within tile (consecutive lanes -> consecutive n)
  const int wkq = (tid >> 6) << 4;   // 0,16,32,48 (k-quarter per wave)

  // single raw-f32 prefetch bank
  float4 xf[4][2];
  float  wv[16];

#define LOADREGS(KT) do {                                                        \
    const int r_  = (KT) >> 10;                                                  \
    const int i0_ = (KT) & 1023;                                                 \
    _Pragma("unroll")                                                            \
    for (int p_ = 0; p_ < 4; ++p_) {                                             \
      if (xtk[p_] >= 0) {                                                        \
        const float* sp_ = x + ((size_t)r_ * TKN + xtk[p_]) * IPR + i0_ + xc;    \
        xf[p_][0] = *reinterpret_cast<const float4*>(sp_);                       \
        xf[p_][1] = *reinterpret_cast<const float4*>(sp_ + 4);                   \
      } else {                                                                   \
        xf[p_][0] = float4{0.f, 0.f, 0.f, 0.f};                                  \
        xf[p_][1] = float4{0.f, 0.f, 0.f, 0.f};                                  \
      }                                                                          \
    }                                                                            \
    const float* wp_ = w + (((size_t)r_ * NE + e) * IPR + i0_ + wkq) * HD + n0 + wn; \
    _Pragma("unroll")                                                            \
    for (int j_ = 0; j_ < 16; ++j_) wv[j_] = wp_[(size_t)j_ * HD];               \
  } while (0)

  f32x4 acc[4][2];
#pragma unroll
  for (int a = 0; a < 4; ++a)
#pragma unroll
    for (int b = 0; b < 2; ++b) acc[a][b] = f32x4{0.f, 0.f, 0.f, 0.f};

  const int lrow = lane & 15;
  const int lk   = (lane >> 4) << 3;   // 0,8,16,24

  LOADREGS(0);

  for (int t = 0; t < NIT; ++t) {
    BAR();   // previous compute's LDS reads drained; LDS free

    // ---- write prefetched regs -> LDS (f32 -> bf16) ----
#pragma unroll
    for (int p = 0; p < 4; ++p) {
      u16x8 v;
      v[0] = f2b(xf[p][0].x); v[1] = f2b(xf[p][0].y);
      v[2] = f2b(xf[p][0].z); v[3] = f2b(xf[p][0].w);
      v[4] = f2b(xf[p][1].x); v[5] = f2b(xf[p][1].y);
      v[6] = f2b(xf[p][1].z); v[7] = f2b(xf[p][1].w);
      *reinterpret_cast<u16x8*>(&Xs[p * 32 + xr][xc]) = v;
    }
    {
      u16x8 a, b;
      a[0] = f2b(wv[0]);  a[1] = f2b(wv[1]);  a[2] = f2b(wv[2]);  a[3] = f2b(wv[3]);
      a[4] = f2b(wv[4]);  a[5] = f2b(wv[5]);  a[6] = f2b(wv[6]);  a[7] = f2b(wv[7]);
      b[0] = f2b(wv[8]);  b[1] = f2b(wv[9]);  b[2] = f2b(wv[10]); b[3] = f2b(wv[11]);
      b[4] = f2b(wv[12]); b[5] = f2b(wv[13]); b[6] = f2b(wv[14]); b[7] = f2b(wv[15]);
      *reinterpret_cast<u16x8*>(&Ws[wn][wkq])     = a;
      *reinterpret_cast<u16x8*>(&Ws[wn][wkq + 8]) = b;
    }
    BAR();   // ds_writes visible to all waves

    // ---- prefetch next iteration (overlaps compute below) ----
    if (t + 1 < NIT) LOADREGS((t + 1) * BK);

    // ---- compute: 2 k-steps of 32, 4x2 fragments per wave ----
#pragma unroll
    for (int ks = 0; ks < 2; ++ks) {
      bf16x8 af[4], bfr[2];
#pragma unroll
      for (int mi = 0; mi < 4; ++mi)
        af[mi] = __builtin_bit_cast(bf16x8,
            *reinterpret_cast<const u16x8*>(&Xs[wr * 64 + mi * 16 + lrow][ks * 32 + lk]));
#pragma unroll
      for (int ni = 0; ni < 2; ++ni)
        bfr[ni] = __builtin_bit_cast(bf16x8,
            *reinterpret_cast<const u16x8*>(&Ws[wc * 32 + ni * 16 + lrow][ks * 32 + lk]));
#pragma unroll
      for (int mi = 0; mi < 4; ++mi)
#pragma unroll
        for (int ni = 0; ni < 2; ++ni)
          acc[mi][ni] = __builtin_amdgcn_mfma_f32_16x16x32_bf16(af[mi], bfr[ni], acc[mi][ni], 0, 0, 0);
    }
  }

  // ---- epilogue: gate * acc, atomicAdd into f32 out (exactly 2 adds/element) ----
  const int mb = (lane >> 4) << 2;
#pragma unroll
  for (int mi = 0; mi < 4; ++mi) {
#pragma unroll
    for (int q = 0; q < 4; ++q) {
      const int m = wr * 64 + mi * 16 + mb + q;
      if (m < nr) {
        const int tk = perm[row0 + m];
        const float g = gate[tk];
        float* dst = out + (size_t)(tk >> 1) * HD + n0 + wc * 32 + lrow;
#pragma unroll
        for (int ni = 0; ni < 2; ++ni)
          atomicAdd(&dst[ni * 16], g * acc[mi][ni][q]);
      }
    }
  }
#undef LOADREGS
}

extern "C" void kernel_launch(void* const* d_in, const int* in_sizes, int n_in,
                              void* d_out, int out_size, void* d_ws, size_t ws_size,
                              hipStream_t stream) {
  const float* x      = (const float*)d_in[0];  // f32 (upcast from fp16)
  const float* w      = (const float*)d_in[1];  // f32 (upcast from fp16)
  const float* logits = (const float*)d_in[2];
  // d_in[3] = topk (constant 2), unused

  char* ws = (char*)d_ws;
  float* gate    = (float*)(ws + 0);          // TKN floats   (8 KB)
  int*   perm    = (int*)(ws + 8192);         // TKN ints     (8 KB)
  int*   tile_e  = (int*)(ws + 16384);        // MAXTILES ints
  int*   tile_r0 = (int*)(ws + 16384 + 256);
  int*   tile_nr = (int*)(ws + 16384 + 512);

  float* outf = (float*)d_out;                // f32 output [NTOK][HD]

  zero_kernel<<<(NTOK * HD / 4) / 256, 256, 0, stream>>>(outf);
  routing_kernel<<<1, 1024, 0, stream>>>(logits, gate, perm, tile_e, tile_r0, tile_nr);
  gemm_kernel<<<NWG, 256, 0, stream>>>(x, w, perm, tile_e, tile_r0, tile_nr, gate, outf);
}